// Round 3
// baseline (270.801 us; speedup 1.0000x reference)
//
#include <hip/hip_runtime.h>

// SSIM, fused separable, barrier-free column-sliding register design.
// Each thread owns one output column of a 256x64 strip and slides down 74 rows.
// Horizontal 11-tap window loaded directly from global (L1/L2-served, 3x float4
// per image); per-lane zero-masked weights Wp[12] handle x-edges; vertical pass
// is a 4-quantity x 11-deep register ring (SSIM needs only blur(x), blur(y),
// blur(x^2+y^2), blur(xy)). No LDS staging, no barriers in the main loop.

#define IMG_H 512
#define IMG_W 512
#define N_PLANES 48
#define KW 11
#define RING 11
#define STRIP_W 256
#define STRIP_H 64
#define BLOCK 256
#define STRIPS_X (IMG_W / STRIP_W)             // 2
#define STRIPS_Y (IMG_H / STRIP_H)             // 8
#define NBLK (N_PLANES * STRIPS_X * STRIPS_Y)  // 768
#define C1_CONST 1.0e-4f
#define C2_CONST 9.0e-4f

__device__ __forceinline__ float bcastf(float x) {
  return __uint_as_float(__builtin_amdgcn_readfirstlane(__float_as_uint(x)));
}

#define TAP(E, AV, BV) { const float w_ = Wp[(E)]; \
    const float t1_ = w_ * (AV); const float t2_ = w_ * (BV); \
    m1_ += t1_; m2_ += t2_; \
    q12_ += t1_ * (BV); qs_ += t1_ * (AV); qs_ += t2_ * (BV); }

#define EMTAP(K, Q) { const float w_ = wkr[(K)]; \
    vm1_ += w_ * rm1[(Q)]; vm2_ += w_ * rm2[(Q)]; \
    vqs_ += w_ * rqs[(Q)]; vq12_ += w_ * rq12[(Q)]; }

#define STEP(P, EMIT) { \
  if (gr >= 0 && gr < IMG_H) { \
    const float* __restrict__ r1_ = p1 + (size_t)gr * IMG_W + base_c; \
    const float* __restrict__ r2_ = p2 + (size_t)gr * IMG_W + base_c; \
    float4 A0, A1, A2, B0, B1, B2; \
    __builtin_memcpy(&A0, r1_,     16); \
    __builtin_memcpy(&A1, r1_ + 4, 16); \
    __builtin_memcpy(&A2, r1_ + 8, 16); \
    __builtin_memcpy(&B0, r2_,     16); \
    __builtin_memcpy(&B1, r2_ + 4, 16); \
    __builtin_memcpy(&B2, r2_ + 8, 16); \
    float m1_ = 0.f, m2_ = 0.f, qs_ = 0.f, q12_ = 0.f; \
    TAP(0, A0.x, B0.x) TAP(1, A0.y, B0.y) TAP(2, A0.z, B0.z) TAP(3, A0.w, B0.w) \
    TAP(4, A1.x, B1.x) TAP(5, A1.y, B1.y) TAP(6, A1.z, B1.z) TAP(7, A1.w, B1.w) \
    TAP(8, A2.x, B2.x) TAP(9, A2.y, B2.y) TAP(10, A2.z, B2.z) TAP(11, A2.w, B2.w) \
    rm1[(P)] = m1_; rm2[(P)] = m2_; rqs[(P)] = qs_; rq12[(P)] = q12_; \
  } else { \
    rm1[(P)] = 0.f; rm2[(P)] = 0.f; rqs[(P)] = 0.f; rq12[(P)] = 0.f; \
  } \
  if (EMIT) { \
    float vm1_ = 0.f, vm2_ = 0.f, vqs_ = 0.f, vq12_ = 0.f; \
    EMTAP(0, ((P)+1)%RING)  EMTAP(1, ((P)+2)%RING)  EMTAP(2, ((P)+3)%RING) \
    EMTAP(3, ((P)+4)%RING)  EMTAP(4, ((P)+5)%RING)  EMTAP(5, ((P)+6)%RING) \
    EMTAP(6, ((P)+7)%RING)  EMTAP(7, ((P)+8)%RING)  EMTAP(8, ((P)+9)%RING) \
    EMTAP(9, ((P)+10)%RING) EMTAP(10, (P)) \
    const float mu11_ = vm1_ * vm1_; \
    const float mu22_ = vm2_ * vm2_; \
    const float mu12_ = vm1_ * vm2_; \
    const float musum_ = mu11_ + mu22_; \
    const float sigs_  = vqs_  - musum_; \
    const float sig12_ = vq12_ - mu12_; \
    const float num_ = (2.f * mu12_ + C1_CONST) * (2.f * sig12_ + C2_CONST); \
    const float den_ = (musum_ + C1_CONST) * (sigs_ + C2_CONST); \
    acc += num_ * __builtin_amdgcn_rcpf(den_); \
  } \
  gr++; \
}

__global__ __launch_bounds__(BLOCK, 4) void ssim_strip_kernel(
    const float* __restrict__ img1,
    const float* __restrict__ img2,
    const float* __restrict__ kern2d,
    float* __restrict__ partial)
{
  __shared__ float wk_lds[KW];
  __shared__ float wave_sums[BLOCK / 64];

  const int tid = threadIdx.x;

  // 1D kernel = row sums of the normalized 2D kernel (== normalized 1D Gaussian).
  if (tid < KW) {
    float s = 0.f;
    #pragma unroll
    for (int j = 0; j < KW; ++j) s += kern2d[tid * KW + j];
    wk_lds[tid] = s;
  }
  __syncthreads();

  // V-pass weights in SGPRs (wave-uniform).
  float wkr[RING];
  #pragma unroll
  for (int k = 0; k < RING; ++k) wkr[k] = bcastf(wk_lds[k]);

  const int bid   = blockIdx.x;
  const int plane = bid / (STRIPS_X * STRIPS_Y);
  const int srem  = bid % (STRIPS_X * STRIPS_Y);
  const int y0    = (srem / STRIPS_X) * STRIP_H;
  const int x0    = (srem % STRIPS_X) * STRIP_W;
  const float* __restrict__ p1 = img1 + (size_t)plane * IMG_H * IMG_W;
  const float* __restrict__ p2 = img2 + (size_t)plane * IMG_H * IMG_W;

  const int gx = x0 + tid;                 // this thread's output column
  int bc = gx - 5;                         // desired window start
  const int base_c = bc < 0 ? 0 : (bc > IMG_W - 12 ? IMG_W - 12 : bc);

  // Per-lane H-pass weights over the 12 loaded columns (zero outside the
  // 11-tap window / image bounds). wk_lds read is runtime-indexed -> LDS, fine.
  float Wp[12];
  #pragma unroll
  for (int e = 0; e < 12; ++e) {
    const int col = base_c + e;
    const int k = col - (gx - 5);
    Wp[e] = (k >= 0 && k <= 10 && col < IMG_W) ? wk_lds[k] : 0.f;
  }

  float rm1[RING], rm2[RING], rqs[RING], rq12[RING];
  float acc = 0.f;
  int gr = y0 - 5;

  // 74 steps: 10 warmup, 64 emitting. Phase = step % 11 (compile-time).
  STEP(0, 0) STEP(1, 0) STEP(2, 0) STEP(3, 0) STEP(4, 0)
  STEP(5, 0) STEP(6, 0) STEP(7, 0) STEP(8, 0) STEP(9, 0)
  STEP(10, 1)
  #pragma unroll 1
  for (int it = 0; it < 5; ++it) {
    STEP(0, 1) STEP(1, 1) STEP(2, 1) STEP(3, 1) STEP(4, 1) STEP(5, 1)
    STEP(6, 1) STEP(7, 1) STEP(8, 1) STEP(9, 1) STEP(10, 1)
  }
  STEP(0, 1) STEP(1, 1) STEP(2, 1) STEP(3, 1)
  STEP(4, 1) STEP(5, 1) STEP(6, 1) STEP(7, 1)

  // Block reduction.
  #pragma unroll
  for (int off = 32; off > 0; off >>= 1)
    acc += __shfl_down(acc, off, 64);
  if ((tid & 63) == 0) wave_sums[tid >> 6] = acc;
  __syncthreads();
  if (tid == 0)
    partial[bid] = wave_sums[0] + wave_sums[1] + wave_sums[2] + wave_sums[3];
}

__global__ __launch_bounds__(256) void ssim_reduce_kernel(
    const float* __restrict__ partial, float* __restrict__ out)
{
  const int tid = threadIdx.x;
  double acc = 0.0;
  for (int i = tid; i < NBLK; i += 256) acc += (double)partial[i];
  #pragma unroll
  for (int off = 32; off > 0; off >>= 1)
    acc += __shfl_down(acc, off, 64);
  __shared__ double wsums[4];
  if ((tid & 63) == 0) wsums[tid >> 6] = acc;
  __syncthreads();
  if (tid == 0) {
    const double total = wsums[0] + wsums[1] + wsums[2] + wsums[3];
    const double inv_n = 1.0 / ((double)N_PLANES * IMG_H * IMG_W);
    out[0] = (float)(total * inv_n);
  }
}

extern "C" void kernel_launch(void* const* d_in, const int* in_sizes, int n_in,
                              void* d_out, int out_size, void* d_ws, size_t ws_size,
                              hipStream_t stream)
{
  const float* img1 = (const float*)d_in[0];
  const float* img2 = (const float*)d_in[1];
  const float* kern = (const float*)d_in[2];
  float* out = (float*)d_out;
  float* partial = (float*)d_ws;   // NBLK floats = 3 KiB

  ssim_strip_kernel<<<NBLK, BLOCK, 0, stream>>>(img1, img2, kern, partial);
  ssim_reduce_kernel<<<1, 256, 0, stream>>>(partial, out);
}

// Round 4
// 120.591 us; speedup vs baseline: 2.2456x; 2.2456x over previous
//
#include <hip/hip_runtime.h>

// SSIM, fused separable, barrier-free column-sliding register design (fixed).
// Each thread owns one output column of a 256x32 strip, slides down 42 rows.
// H-window loaded directly from global (3x dwordx4 per image, L1/L2-served);
// per-lane zero-masked weights Wp[12] handle x-edges; V-pass is a 4-quantity
// x 11-deep register ring (blur(x), blur(y), blur(x^2+y^2), blur(xy)).
// No LDS staging, no barriers in the main loop, no launch-bounds VGPR cap
// (R3's __launch_bounds__(256,4) forced a 128-VGPR cap -> full scratch spill,
// 315 MB of local-memory writes).

#define IMG_H 512
#define IMG_W 512
#define N_PLANES 48
#define KW 11
#define RING 11
#define STRIP_W 256
#define STRIP_H 32
#define BLOCK 256
#define STRIPS_X (IMG_W / STRIP_W)             // 2
#define STRIPS_Y (IMG_H / STRIP_H)             // 16
#define NBLK (N_PLANES * STRIPS_X * STRIPS_Y)  // 1536
#define C1_CONST 1.0e-4f
#define C2_CONST 9.0e-4f

__device__ __forceinline__ float bcastf(float x) {
  return __uint_as_float(__builtin_amdgcn_readfirstlane(__float_as_uint(x)));
}

#define TAP(E, AV, BV) { const float w_ = Wp[(E)]; \
    const float t1_ = w_ * (AV); const float t2_ = w_ * (BV); \
    m1_ += t1_; m2_ += t2_; \
    q12_ += t1_ * (BV); qs_ += t1_ * (AV); qs_ += t2_ * (BV); }

#define EMTAP(K, Q) { const float w_ = wkr[(K)]; \
    vm1_ += w_ * rm1[(Q)]; vm2_ += w_ * rm2[(Q)]; \
    vqs_ += w_ * rqs[(Q)]; vq12_ += w_ * rq12[(Q)]; }

#define STEP(P, EMIT) { \
  if (gr >= 0 && gr < IMG_H) { \
    const float* __restrict__ r1_ = p1 + (size_t)gr * IMG_W + base_c; \
    const float* __restrict__ r2_ = p2 + (size_t)gr * IMG_W + base_c; \
    float4 A0, A1, A2, B0, B1, B2; \
    __builtin_memcpy(&A0, r1_,     16); \
    __builtin_memcpy(&A1, r1_ + 4, 16); \
    __builtin_memcpy(&A2, r1_ + 8, 16); \
    __builtin_memcpy(&B0, r2_,     16); \
    __builtin_memcpy(&B1, r2_ + 4, 16); \
    __builtin_memcpy(&B2, r2_ + 8, 16); \
    float m1_ = 0.f, m2_ = 0.f, qs_ = 0.f, q12_ = 0.f; \
    TAP(0, A0.x, B0.x) TAP(1, A0.y, B0.y) TAP(2, A0.z, B0.z) TAP(3, A0.w, B0.w) \
    TAP(4, A1.x, B1.x) TAP(5, A1.y, B1.y) TAP(6, A1.z, B1.z) TAP(7, A1.w, B1.w) \
    TAP(8, A2.x, B2.x) TAP(9, A2.y, B2.y) TAP(10, A2.z, B2.z) TAP(11, A2.w, B2.w) \
    rm1[(P)] = m1_; rm2[(P)] = m2_; rqs[(P)] = qs_; rq12[(P)] = q12_; \
  } else { \
    rm1[(P)] = 0.f; rm2[(P)] = 0.f; rqs[(P)] = 0.f; rq12[(P)] = 0.f; \
  } \
  if (EMIT) { \
    float vm1_ = 0.f, vm2_ = 0.f, vqs_ = 0.f, vq12_ = 0.f; \
    EMTAP(0, ((P)+1)%RING)  EMTAP(1, ((P)+2)%RING)  EMTAP(2, ((P)+3)%RING) \
    EMTAP(3, ((P)+4)%RING)  EMTAP(4, ((P)+5)%RING)  EMTAP(5, ((P)+6)%RING) \
    EMTAP(6, ((P)+7)%RING)  EMTAP(7, ((P)+8)%RING)  EMTAP(8, ((P)+9)%RING) \
    EMTAP(9, ((P)+10)%RING) EMTAP(10, (P)) \
    const float mu11_ = vm1_ * vm1_; \
    const float mu22_ = vm2_ * vm2_; \
    const float mu12_ = vm1_ * vm2_; \
    const float musum_ = mu11_ + mu22_; \
    const float sigs_  = vqs_  - musum_; \
    const float sig12_ = vq12_ - mu12_; \
    const float num_ = (2.f * mu12_ + C1_CONST) * (2.f * sig12_ + C2_CONST); \
    const float den_ = (musum_ + C1_CONST) * (sigs_ + C2_CONST); \
    acc += num_ * __builtin_amdgcn_rcpf(den_); \
  } \
  gr++; \
}

__global__ __launch_bounds__(BLOCK) void ssim_strip_kernel(
    const float* __restrict__ img1,
    const float* __restrict__ img2,
    const float* __restrict__ kern2d,
    float* __restrict__ partial)
{
  __shared__ float wk_lds[KW];
  __shared__ float wave_sums[BLOCK / 64];

  const int tid = threadIdx.x;

  // 1D kernel = row sums of the normalized 2D kernel (== normalized 1D Gaussian).
  if (tid < KW) {
    float s = 0.f;
    #pragma unroll
    for (int j = 0; j < KW; ++j) s += kern2d[tid * KW + j];
    wk_lds[tid] = s;
  }
  __syncthreads();

  // V-pass weights in SGPRs (wave-uniform).
  float wkr[RING];
  #pragma unroll
  for (int k = 0; k < RING; ++k) wkr[k] = bcastf(wk_lds[k]);

  const int bid   = blockIdx.x;
  const int plane = bid / (STRIPS_X * STRIPS_Y);
  const int srem  = bid % (STRIPS_X * STRIPS_Y);
  const int y0    = (srem / STRIPS_X) * STRIP_H;
  const int x0    = (srem % STRIPS_X) * STRIP_W;
  const float* __restrict__ p1 = img1 + (size_t)plane * IMG_H * IMG_W;
  const float* __restrict__ p2 = img2 + (size_t)plane * IMG_H * IMG_W;

  const int gx = x0 + tid;                 // this thread's output column
  const int bc = gx - 5;                   // desired window start
  const int base_c = bc < 0 ? 0 : (bc > IMG_W - 12 ? IMG_W - 12 : bc);

  // Per-lane H-pass weights over the 12 loaded columns (zero outside the
  // 11-tap window / image bounds).
  float Wp[12];
  #pragma unroll
  for (int e = 0; e < 12; ++e) {
    const int col = base_c + e;
    const int k = col - bc;
    Wp[e] = (k >= 0 && k <= 10 && col < IMG_W) ? wk_lds[k] : 0.f;
  }

  float rm1[RING], rm2[RING], rqs[RING], rq12[RING];
  float acc = 0.f;
  int gr = y0 - 5;

  // 42 steps: 10 warmup, 32 emitting. Phase = step % 11 (compile-time).
  STEP(0, 0) STEP(1, 0) STEP(2, 0) STEP(3, 0) STEP(4, 0)
  STEP(5, 0) STEP(6, 0) STEP(7, 0) STEP(8, 0) STEP(9, 0)
  STEP(10, 1)
  #pragma unroll 1
  for (int it = 0; it < 2; ++it) {
    STEP(0, 1) STEP(1, 1) STEP(2, 1) STEP(3, 1) STEP(4, 1) STEP(5, 1)
    STEP(6, 1) STEP(7, 1) STEP(8, 1) STEP(9, 1) STEP(10, 1)
  }
  STEP(0, 1) STEP(1, 1) STEP(2, 1) STEP(3, 1) STEP(4, 1)
  STEP(5, 1) STEP(6, 1) STEP(7, 1) STEP(8, 1)

  // Block reduction.
  #pragma unroll
  for (int off = 32; off > 0; off >>= 1)
    acc += __shfl_down(acc, off, 64);
  if ((tid & 63) == 0) wave_sums[tid >> 6] = acc;
  __syncthreads();
  if (tid == 0)
    partial[bid] = wave_sums[0] + wave_sums[1] + wave_sums[2] + wave_sums[3];
}

__global__ __launch_bounds__(256) void ssim_reduce_kernel(
    const float* __restrict__ partial, float* __restrict__ out)
{
  const int tid = threadIdx.x;
  double acc = 0.0;
  for (int i = tid; i < NBLK; i += 256) acc += (double)partial[i];
  #pragma unroll
  for (int off = 32; off > 0; off >>= 1)
    acc += __shfl_down(acc, off, 64);
  __shared__ double wsums[4];
  if ((tid & 63) == 0) wsums[tid >> 6] = acc;
  __syncthreads();
  if (tid == 0) {
    const double total = wsums[0] + wsums[1] + wsums[2] + wsums[3];
    const double inv_n = 1.0 / ((double)N_PLANES * IMG_H * IMG_W);
    out[0] = (float)(total * inv_n);
  }
}

extern "C" void kernel_launch(void* const* d_in, const int* in_sizes, int n_in,
                              void* d_out, int out_size, void* d_ws, size_t ws_size,
                              hipStream_t stream)
{
  const float* img1 = (const float*)d_in[0];
  const float* img2 = (const float*)d_in[1];
  const float* kern = (const float*)d_in[2];
  float* out = (float*)d_out;
  float* partial = (float*)d_ws;   // NBLK floats = 6 KiB

  ssim_strip_kernel<<<NBLK, BLOCK, 0, stream>>>(img1, img2, kern, partial);
  ssim_reduce_kernel<<<1, 256, 0, stream>>>(partial, out);
}